// Round 3
// baseline (549.250 us; speedup 1.0000x reference)
//
#include <hip/hip_runtime.h>
#include <stdint.h>

#define DEV __device__ __forceinline__

using f32x4  = __attribute__((ext_vector_type(4))) float;
using bf16x8 = __attribute__((ext_vector_type(8))) __bf16;
using bf16x4 = __attribute__((ext_vector_type(4))) __bf16;

static constexpr int SEQ  = 2048;
static constexpr int FEA  = 1024;
static constexpr int NHEAD = 16;
static constexpr int MROWS = 4096;  // B*S
// scale folded into Wq: (1/sqrt(64)) * log2(e)  -> scores directly in exp2 domain
static constexpr float QK_SCALE = 0.18033688011112042f;

DEV f32x4 mfma16(bf16x8 a, bf16x8 b, f32x4 c) {
  return __builtin_amdgcn_mfma_f32_16x16x32_bf16(a, b, c, 0, 0, 0);
}

DEV void gload16(const void* g, void* l) {
  __builtin_amdgcn_global_load_lds((__attribute__((address_space(1))) void*)g,
                                   (__attribute__((address_space(3))) void*)l,
                                   16, 0, 0);
}

// ---------------------------------------------------------------- convert ---
struct ConvSeg { const float* src; __bf16* dst; int n4; float scale; };
struct ConvArgs { ConvSeg seg[7]; };

__global__ __launch_bounds__(256) void convert_k(ConvArgs a) {
  const ConvSeg sg = a.seg[blockIdx.y];
  const int stride = gridDim.x * blockDim.x;
  for (int i = blockIdx.x * blockDim.x + threadIdx.x; i < sg.n4; i += stride) {
    const f32x4 v = *(const f32x4*)(sg.src + (size_t)i * 4);
    bf16x4 o = {(__bf16)(v[0] * sg.scale), (__bf16)(v[1] * sg.scale),
                (__bf16)(v[2] * sg.scale), (__bf16)(v[3] * sg.scale)};
    *(bf16x4*)(sg.dst + (size_t)i * 4) = o;
  }
}

// ------------------------------------------------------------------- GEMM ---
// Shared 128x128-tile, 4-wave, 16x16x32 bf16 main loop (m97 structure).
DEV void gemm_core(const __bf16* __restrict__ A, const __bf16* __restrict__ Bt,
                   char* lds, int row0, int col0, int tid, f32x4 (&acc)[4][4]) {
  char* Alds = lds;
  char* Blds = lds + 8192;
  constexpr int K = 1024;
  const int lane = tid & 63;
  const int w    = tid >> 6;
  const int ci   = lane & 15;
  const int g    = lane >> 4;
  const int wr   = w >> 1, wc = w & 1;

  const int c0 = tid, c1 = tid + 256;
  const __bf16* ga0 = A  + (size_t)(row0 + (c0 >> 2)) * K + (c0 & 3) * 8;
  const __bf16* ga1 = A  + (size_t)(row0 + (c1 >> 2)) * K + (c1 & 3) * 8;
  const __bf16* gb0 = Bt + (size_t)(col0 + (c0 >> 2)) * K + (c0 & 3) * 8;
  const __bf16* gb1 = Bt + (size_t)(col0 + (c1 >> 2)) * K + (c1 & 3) * 8;
  char* la0 = Alds + c0 * 16;
  char* la1 = Alds + c1 * 16;
  char* lb0 = Blds + c0 * 16;
  char* lb1 = Blds + c1 * 16;

  for (int k0 = 0; k0 < K; k0 += 32) {
    __syncthreads();
    gload16(ga0 + k0, la0);
    gload16(ga1 + k0, la1);
    gload16(gb0 + k0, lb0);
    gload16(gb1 + k0, lb1);
    __syncthreads();
    bf16x8 af[4], bfr[4];
#pragma unroll
    for (int m = 0; m < 4; ++m)
      af[m] = *(const bf16x8*)(Alds + ((wr * 64 + m * 16 + ci) * 32 + g * 8) * 2);
#pragma unroll
    for (int n = 0; n < 4; ++n)
      bfr[n] = *(const bf16x8*)(Blds + ((wc * 64 + n * 16 + ci) * 32 + g * 8) * 2);
#pragma unroll
    for (int m = 0; m < 4; ++m)
#pragma unroll
      for (int n = 0; n < 4; ++n)
        acc[m][n] = mfma16(af[m], bfr[n], acc[m][n]);
  }
}

// Batched q/k/v projection: grid.z picks the problem. z=0,1 -> [B,H,S,D]; z=2 -> [B,H,D,S].
struct QkvArgs {
  const __bf16* A[3];
  const __bf16* Bt[3];
  const float*  bias[3];
  float         bscale[3];
  __bf16*       out[3];
};

__global__ __launch_bounds__(256) void gemm_qkv(QkvArgs args) {
  __shared__ __align__(16) char lds[16384];
  const int z = blockIdx.z;
  const int tid = threadIdx.x;
  const int row0 = blockIdx.x * 128;
  const int col0 = blockIdx.y * 128;
  f32x4 acc[4][4] = {};
  gemm_core(args.A[z], args.Bt[z], lds, row0, col0, tid, acc);

  const int lane = tid & 63;
  const int ci = lane & 15, g = lane >> 4;
  const int w = tid >> 6;
  const int wr = w >> 1, wc = w & 1;
  const float* bias = args.bias[z];
  const float bscale = args.bscale[z];
  __bf16* outp = args.out[z];
  const bool vt = (z == 2);
#pragma unroll
  for (int m = 0; m < 4; ++m)
#pragma unroll
    for (int n = 0; n < 4; ++n)
#pragma unroll
      for (int r = 0; r < 4; ++r) {
        const int gr = row0 + wr * 64 + m * 16 + 4 * g + r;
        const int gc = col0 + wc * 64 + n * 16 + ci;
        const float vv = acc[m][n][r] + bias[gc] * bscale;
        const int b = gr >> 11, s = gr & (SEQ - 1);
        const int h = gc >> 6,  d = gc & 63;
        if (!vt)
          outp[(((size_t)b * NHEAD + h) * SEQ + s) * 64 + d] = (__bf16)vv;
        else
          outp[(((size_t)b * NHEAD + h) * 64 + d) * SEQ + s] = (__bf16)vv;
      }
}

__global__ __launch_bounds__(256) void gemm_fc(const __bf16* __restrict__ A,
                                               const __bf16* __restrict__ Bt,
                                               const float* __restrict__ bias,
                                               float* __restrict__ outp) {
  __shared__ __align__(16) char lds[16384];
  const int tid = threadIdx.x;
  const int row0 = blockIdx.x * 128;
  const int col0 = blockIdx.y * 128;
  f32x4 acc[4][4] = {};
  gemm_core(A, Bt, lds, row0, col0, tid, acc);

  const int lane = tid & 63;
  const int ci = lane & 15, g = lane >> 4;
  const int w = tid >> 6;
  const int wr = w >> 1, wc = w & 1;
#pragma unroll
  for (int m = 0; m < 4; ++m)
#pragma unroll
    for (int n = 0; n < 4; ++n)
#pragma unroll
      for (int r = 0; r < 4; ++r) {
        const int gr = row0 + wr * 64 + m * 16 + 4 * g + r;
        const int gc = col0 + wc * 64 + n * 16 + ci;
        const float vv = fmaxf(acc[m][n][r] + bias[gc], 0.0f);
        __builtin_nontemporal_store(vv, &outp[(size_t)gr * FEA + gc]);
      }
}

// -------------------------------------------------------------- attention ---
// One block = 16 q-rows of one (b,h). 512 thr (8 waves). Two-pass, no E tile.
// Pass 1: swapped QK^T (mfma(K,Q)) in exp2-domain -> per-row sum of exp2 -> linv.
// Pass 2: recompute QK^T; e = exp2(sf + linv); stream normalized fp32 attn
//         directly from registers (nontemporal, full 128B lines per row);
//         PV via permuted virtual-k MFMA: A-frag from own lanes' e (4 cvt,
//         no shuffles), B-frag = two bf16x4 gathers from VhT in same order.
__global__ __launch_bounds__(512, 4) void attn_fused(const __bf16* __restrict__ Qh,
                                                     const __bf16* __restrict__ Kh,
                                                     const __bf16* __restrict__ VhT,
                                                     float* __restrict__ attn_out,
                                                     __bf16* __restrict__ Cbuf) {
  __shared__ float pv_lds[8][1088];  // [wave][dt*272 + q*17 + d15], padded
  __shared__ float rs_lds[8][16];
  __shared__ float linv_lds[16];

  const int tid  = threadIdx.x;
  const int lane = tid & 63;
  const int w    = tid >> 6;
  const int ci   = lane & 15;
  const int g    = lane >> 4;

  // XCD-aware swizzle: each XCD (id&7) owns 4 heads -> K/V working set 2MB < L2
  const int id   = blockIdx.x;
  const int xcd  = id & 7;
  const int idx  = id >> 3;
  const int bh   = xcd * 4 + (idx >> 7);
  const int qblk = idx & 127;

  const __bf16* Qp = Qh  + ((size_t)bh * SEQ + qblk * 16) * 64;
  const __bf16* Kp = Kh  + (size_t)bh * SEQ * 64;
  const __bf16* Vp = VhT + (size_t)bh * 64 * SEQ;

  // Q fragments (rows ci, d split 2x32) -- used as MFMA *B* operand
  const bf16x8 aq0 = *(const bf16x8*)(Qp + ci * 64 + 8 * g);
  const bf16x8 aq1 = *(const bf16x8*)(Qp + ci * 64 + 32 + 8 * g);

  const int kbase = w * 256;                        // this wave's 256 k-cols
  const __bf16* kb = Kp + (size_t)(kbase + ci) * 64 + 8 * g;

  // ---- pass 1: rowsums ----
  float rs = 0.f;
#pragma unroll 2
  for (int it = 0; it < 8; ++it) {
    const __bf16* kp = kb + (size_t)it * 32 * 64;
    const bf16x8 kA0 = *(const bf16x8*)(kp);
    const bf16x8 kA1 = *(const bf16x8*)(kp + 32);
    const bf16x8 kB0 = *(const bf16x8*)(kp + 16 * 64);
    const bf16x8 kB1 = *(const bf16x8*)(kp + 16 * 64 + 32);
    f32x4 sfA = {0.f, 0.f, 0.f, 0.f}, sfB = {0.f, 0.f, 0.f, 0.f};
    sfA = mfma16(kA0, aq0, sfA);
    sfA = mfma16(kA1, aq1, sfA);
    sfB = mfma16(kB0, aq0, sfB);
    sfB = mfma16(kB1, aq1, sfB);
#pragma unroll
    for (int r = 0; r < 4; ++r)
      rs += __builtin_amdgcn_exp2f(sfA[r]) + __builtin_amdgcn_exp2f(sfB[r]);
  }
  rs += __shfl_xor(rs, 16);
  rs += __shfl_xor(rs, 32);
  if (lane < 16) rs_lds[w][lane] = rs;
  __syncthreads();
  if (tid < 16) {
    float t = 0.f;
#pragma unroll
    for (int ww = 0; ww < 8; ++ww) t += rs_lds[ww][tid];
    linv_lds[tid] = -__log2f(t);
  }
  __syncthreads();
  const float linv = linv_lds[ci];

  // ---- pass 2: recompute, stream attn, PV ----
  f32x4 apv[4] = {};
  float* orow = attn_out + ((size_t)bh * SEQ + qblk * 16 + ci) * SEQ + 4 * g;

#pragma unroll 2
  for (int it = 0; it < 8; ++it) {
    const int kcol = kbase + it * 32;
    const __bf16* kp = kb + (size_t)it * 32 * 64;
    const bf16x8 kA0 = *(const bf16x8*)(kp);
    const bf16x8 kA1 = *(const bf16x8*)(kp + 32);
    const bf16x8 kB0 = *(const bf16x8*)(kp + 16 * 64);
    const bf16x8 kB1 = *(const bf16x8*)(kp + 16 * 64 + 32);
    f32x4 sfA = {0.f, 0.f, 0.f, 0.f}, sfB = {0.f, 0.f, 0.f, 0.f};
    sfA = mfma16(kA0, aq0, sfA);
    sfA = mfma16(kA1, aq1, sfA);
    sfB = mfma16(kB0, aq0, sfB);
    sfB = mfma16(kB1, aq1, sfB);
    f32x4 eA, eB;
#pragma unroll
    for (int r = 0; r < 4; ++r) {
      eA[r] = __builtin_amdgcn_exp2f(sfA[r] + linv);
      eB[r] = __builtin_amdgcn_exp2f(sfB[r] + linv);
    }
    // normalized fp32 attn, straight from registers
    __builtin_nontemporal_store(eA, (f32x4*)(orow + kcol));
    __builtin_nontemporal_store(eB, (f32x4*)(orow + kcol + 16));
    // PV A-fragment: virtual k-slot 8g+j -> cols {kcol+4g..+3, kcol+16+4g..+3}
    bf16x8 pa = {(__bf16)eA[0], (__bf16)eA[1], (__bf16)eA[2], (__bf16)eA[3],
                 (__bf16)eB[0], (__bf16)eB[1], (__bf16)eB[2], (__bf16)eB[3]};
#pragma unroll
    for (int dt = 0; dt < 4; ++dt) {
      const __bf16* vp = Vp + (size_t)(dt * 16 + ci) * SEQ + kcol + 4 * g;
      const bf16x4 v0 = *(const bf16x4*)(vp);
      const bf16x4 v1 = *(const bf16x4*)(vp + 16);
      const bf16x8 vb = {v0[0], v0[1], v0[2], v0[3], v1[0], v1[1], v1[2], v1[3]};
      apv[dt] = mfma16(pa, vb, apv[dt]);
    }
  }

  // cross-wave PV reduction
#pragma unroll
  for (int dt = 0; dt < 4; ++dt)
#pragma unroll
    for (int r = 0; r < 4; ++r)
      pv_lds[w][dt * 272 + (4 * g + r) * 17 + ci] = apv[dt][r];
  __syncthreads();
  {
    const int o  = tid * 2;
    const int qq = o >> 6;
    const int d0 = o & 63, d1 = d0 + 1;
    float s0 = 0.f, s1 = 0.f;
#pragma unroll
    for (int ww = 0; ww < 8; ++ww) {
      s0 += pv_lds[ww][(d0 >> 4) * 272 + qq * 17 + (d0 & 15)];
      s1 += pv_lds[ww][(d1 >> 4) * 272 + qq * 17 + (d1 & 15)];
    }
    const int b = bh >> 4, h = bh & 15;
    __bf16* cp = Cbuf + ((size_t)b * SEQ + qblk * 16 + qq) * FEA + h * 64 + d0;
    cp[0] = (__bf16)s0;
    cp[1] = (__bf16)s1;
  }
}

// ------------------------------------------------------------------ launch ---
extern "C" void kernel_launch(void* const* d_in, const int* in_sizes, int n_in,
                              void* d_out, int out_size, void* d_ws, size_t ws_size,
                              hipStream_t stream) {
  const float* q    = (const float*)d_in[0];
  const float* k    = (const float*)d_in[1];
  const float* v    = (const float*)d_in[2];
  const float* wq_w = (const float*)d_in[3];
  const float* wq_b = (const float*)d_in[4];
  const float* wk_w = (const float*)d_in[5];
  const float* wk_b = (const float*)d_in[6];
  const float* wv_w = (const float*)d_in[7];
  const float* wv_b = (const float*)d_in[8];
  const float* fc_w = (const float*)d_in[9];
  const float* fc_b = (const float*)d_in[10];

  float* out0 = (float*)d_out;
  float* attn = out0 + (size_t)MROWS * FEA;  // second tuple output

  // bf16 scratch that dies before attn runs -> reuse the attn output region
  __bf16* Xq = (__bf16*)attn;
  __bf16* Xk = Xq + (size_t)MROWS * FEA;
  __bf16* Xv = Xk + (size_t)MROWS * FEA;
  __bf16* Wq = Xv + (size_t)MROWS * FEA;
  __bf16* Wk = Wq + (size_t)FEA * FEA;
  __bf16* Wv = Wk + (size_t)FEA * FEA;

  // persistent scratch (lives across attn) -> d_ws, 34 MiB
  __bf16* Qh  = (__bf16*)d_ws;
  __bf16* Kh  = Qh  + (size_t)MROWS * FEA;
  __bf16* VhT = Kh  + (size_t)MROWS * FEA;
  __bf16* Cb  = VhT + (size_t)MROWS * FEA;
  __bf16* Wfc = Cb  + (size_t)MROWS * FEA;

  ConvArgs ca;
  ca.seg[0] = {q,    Xq,  (MROWS * FEA) / 4, 1.0f};
  ca.seg[1] = {k,    Xk,  (MROWS * FEA) / 4, 1.0f};
  ca.seg[2] = {v,    Xv,  (MROWS * FEA) / 4, 1.0f};
  ca.seg[3] = {wq_w, Wq,  (FEA * FEA) / 4,   QK_SCALE};
  ca.seg[4] = {wk_w, Wk,  (FEA * FEA) / 4,   1.0f};
  ca.seg[5] = {wv_w, Wv,  (FEA * FEA) / 4,   1.0f};
  ca.seg[6] = {fc_w, Wfc, (FEA * FEA) / 4,   1.0f};
  convert_k<<<dim3(512, 7), 256, 0, stream>>>(ca);

  QkvArgs qa;
  qa.A[0] = Xq; qa.Bt[0] = Wq; qa.bias[0] = wq_b; qa.bscale[0] = QK_SCALE; qa.out[0] = Qh;
  qa.A[1] = Xk; qa.Bt[1] = Wk; qa.bias[1] = wk_b; qa.bscale[1] = 1.0f;     qa.out[1] = Kh;
  qa.A[2] = Xv; qa.Bt[2] = Wv; qa.bias[2] = wv_b; qa.bscale[2] = 1.0f;     qa.out[2] = VhT;
  gemm_qkv<<<dim3(MROWS / 128, FEA / 128, 3), 256, 0, stream>>>(qa);

  attn_fused<<<dim3(4096), 512, 0, stream>>>(Qh, Kh, VhT, attn, Cb);

  gemm_fc<<<dim3(MROWS / 128, FEA / 128), 256, 0, stream>>>(Cb, Wfc, fc_b, out0);
}

// Round 4
// 239.271 us; speedup vs baseline: 2.2955x; 2.2955x over previous
//
#include <hip/hip_runtime.h>
#include <stdint.h>

#define DEV __device__ __forceinline__

using f32x4  = __attribute__((ext_vector_type(4))) float;
using bf16x8 = __attribute__((ext_vector_type(8))) __bf16;
using bf16x4 = __attribute__((ext_vector_type(4))) __bf16;

static constexpr int SEQ  = 2048;
static constexpr int FEA  = 1024;
static constexpr int NHEAD = 16;
static constexpr int MROWS = 4096;  // B*S
// scale folded into Wq: (1/sqrt(64)) * log2(e)  -> scores directly in exp2 domain
static constexpr float QK_SCALE = 0.18033688011112042f;

DEV f32x4 mfma16(bf16x8 a, bf16x8 b, f32x4 c) {
  return __builtin_amdgcn_mfma_f32_16x16x32_bf16(a, b, c, 0, 0, 0);
}

DEV void gload16(const void* g, void* l) {
  __builtin_amdgcn_global_load_lds((__attribute__((address_space(1))) void*)g,
                                   (__attribute__((address_space(3))) void*)l,
                                   16, 0, 0);
}

// ---------------------------------------------------------------- convert ---
struct ConvSeg { const float* src; __bf16* dst; int n4; float scale; };
struct ConvArgs { ConvSeg seg[7]; };

__global__ __launch_bounds__(256) void convert_k(ConvArgs a) {
  const ConvSeg sg = a.seg[blockIdx.y];
  const int stride = gridDim.x * blockDim.x;
  for (int i = blockIdx.x * blockDim.x + threadIdx.x; i < sg.n4; i += stride) {
    const f32x4 v = *(const f32x4*)(sg.src + (size_t)i * 4);
    bf16x4 o = {(__bf16)(v[0] * sg.scale), (__bf16)(v[1] * sg.scale),
                (__bf16)(v[2] * sg.scale), (__bf16)(v[3] * sg.scale)};
    *(bf16x4*)(sg.dst + (size_t)i * 4) = o;
  }
}

// ------------------------------------------------------------------- GEMM ---
// Shared 128x128-tile, 4-wave, 16x16x32 bf16 main loop (m97 structure).
DEV void gemm_core(const __bf16* __restrict__ A, const __bf16* __restrict__ Bt,
                   char* lds, int row0, int col0, int tid, f32x4 (&acc)[4][4]) {
  char* Alds = lds;
  char* Blds = lds + 8192;
  constexpr int K = 1024;
  const int lane = tid & 63;
  const int w    = tid >> 6;
  const int ci   = lane & 15;
  const int g    = lane >> 4;
  const int wr   = w >> 1, wc = w & 1;

  const int c0 = tid, c1 = tid + 256;
  const __bf16* ga0 = A  + (size_t)(row0 + (c0 >> 2)) * K + (c0 & 3) * 8;
  const __bf16* ga1 = A  + (size_t)(row0 + (c1 >> 2)) * K + (c1 & 3) * 8;
  const __bf16* gb0 = Bt + (size_t)(col0 + (c0 >> 2)) * K + (c0 & 3) * 8;
  const __bf16* gb1 = Bt + (size_t)(col0 + (c1 >> 2)) * K + (c1 & 3) * 8;
  char* la0 = Alds + c0 * 16;
  char* la1 = Alds + c1 * 16;
  char* lb0 = Blds + c0 * 16;
  char* lb1 = Blds + c1 * 16;

  for (int k0 = 0; k0 < K; k0 += 32) {
    __syncthreads();
    gload16(ga0 + k0, la0);
    gload16(ga1 + k0, la1);
    gload16(gb0 + k0, lb0);
    gload16(gb1 + k0, lb1);
    __syncthreads();
    bf16x8 af[4], bfr[4];
#pragma unroll
    for (int m = 0; m < 4; ++m)
      af[m] = *(const bf16x8*)(Alds + ((wr * 64 + m * 16 + ci) * 32 + g * 8) * 2);
#pragma unroll
    for (int n = 0; n < 4; ++n)
      bfr[n] = *(const bf16x8*)(Blds + ((wc * 64 + n * 16 + ci) * 32 + g * 8) * 2);
#pragma unroll
    for (int m = 0; m < 4; ++m)
#pragma unroll
      for (int n = 0; n < 4; ++n)
        acc[m][n] = mfma16(af[m], bfr[n], acc[m][n]);
  }
}

// Batched q/k/v projection: grid.z picks the problem. z=0,1 -> [B,H,S,D]; z=2 -> [B,H,D,S].
struct QkvArgs {
  const __bf16* A[3];
  const __bf16* Bt[3];
  const float*  bias[3];
  float         bscale[3];
  __bf16*       out[3];
};

__global__ __launch_bounds__(256) void gemm_qkv(QkvArgs args) {
  __shared__ __align__(16) char lds[16384];
  const int z = blockIdx.z;
  const int tid = threadIdx.x;
  const int row0 = blockIdx.x * 128;
  const int col0 = blockIdx.y * 128;
  f32x4 acc[4][4] = {};
  gemm_core(args.A[z], args.Bt[z], lds, row0, col0, tid, acc);

  const int lane = tid & 63;
  const int ci = lane & 15, g = lane >> 4;
  const int w = tid >> 6;
  const int wr = w >> 1, wc = w & 1;
  const float* bias = args.bias[z];
  const float bscale = args.bscale[z];
  __bf16* outp = args.out[z];
  const bool vt = (z == 2);
#pragma unroll
  for (int m = 0; m < 4; ++m)
#pragma unroll
    for (int n = 0; n < 4; ++n)
#pragma unroll
      for (int r = 0; r < 4; ++r) {
        const int gr = row0 + wr * 64 + m * 16 + 4 * g + r;
        const int gc = col0 + wc * 64 + n * 16 + ci;
        const float vv = acc[m][n][r] + bias[gc] * bscale;
        const int b = gr >> 11, s = gr & (SEQ - 1);
        const int h = gc >> 6,  d = gc & 63;
        if (!vt)
          outp[(((size_t)b * NHEAD + h) * SEQ + s) * 64 + d] = (__bf16)vv;
        else
          outp[(((size_t)b * NHEAD + h) * 64 + d) * SEQ + s] = (__bf16)vv;
      }
}

__global__ __launch_bounds__(256) void gemm_fc(const __bf16* __restrict__ A,
                                               const __bf16* __restrict__ Bt,
                                               const float* __restrict__ bias,
                                               float* __restrict__ outp) {
  __shared__ __align__(16) char lds[16384];
  const int tid = threadIdx.x;
  const int row0 = blockIdx.x * 128;
  const int col0 = blockIdx.y * 128;
  f32x4 acc[4][4] = {};
  gemm_core(A, Bt, lds, row0, col0, tid, acc);

  const int lane = tid & 63;
  const int ci = lane & 15, g = lane >> 4;
  const int w = tid >> 6;
  const int wr = w >> 1, wc = w & 1;
#pragma unroll
  for (int m = 0; m < 4; ++m)
#pragma unroll
    for (int n = 0; n < 4; ++n)
#pragma unroll
      for (int r = 0; r < 4; ++r) {
        const int gr = row0 + wr * 64 + m * 16 + 4 * g + r;
        const int gc = col0 + wc * 64 + n * 16 + ci;
        const float vv = fmaxf(acc[m][n][r] + bias[gc], 0.0f);
        __builtin_nontemporal_store(vv, &outp[(size_t)gr * FEA + gc]);
      }
}

// -------------------------------------------------------------- attention ---
// One block = 32 q-rows of one (b,h). 512 thr (8 waves): wave = (qg = w>>2, kg = w&3).
// All K/VT tiles staged in LDS via global_load_lds (coalesced, src-pre-swizzled
// XOR ((row&7)<<4)); shared by 8 waves. Two passes over k (rowsums, then
// normalized-store + PV). PV uses virtual-k permutation: A-frag from own
// lane's e regs, B-frag from swizzled VT LDS (b64 pairs in the same order).
static constexpr int QBLK = 32;
static constexpr int KVB  = 128;
static constexpr int NT   = SEQ / KVB;  // 16

__global__ __launch_bounds__(512, 8) void attn_fused(const __bf16* __restrict__ Qh,
                                                     const __bf16* __restrict__ Kh,
                                                     const __bf16* __restrict__ VhT,
                                                     float* __restrict__ attn_out,
                                                     __bf16* __restrict__ Cbuf) {
  __shared__ __align__(16) char smem[34816];  // K(16K)+VT(16K) staging / pv-reduce union
  __shared__ float rs_lds[8][16];
  __shared__ float linv_lds[QBLK];
  char* Klds  = smem;
  char* VTlds = smem + 16384;
  float* pvf  = (float*)smem;

  const int tid  = threadIdx.x;
  const int lane = tid & 63;
  const int w    = tid >> 6;
  const int ci   = lane & 15;
  const int g    = lane >> 4;
  const int qg   = w >> 2;   // 0..1 (q-group of 16 rows)
  const int kg   = w & 3;    // 0..3 (32-k window within tile)

  // XCD-aware swizzle: each XCD owns 4 heads -> K/VT working set 2MB < L2
  const int id   = blockIdx.x;
  const int xcd  = id & 7;
  const int idx  = id >> 3;
  const int bh   = xcd * 4 + (idx >> 6);
  const int qblk = idx & 63;

  const __bf16* Qp   = Qh + ((size_t)bh * SEQ + qblk * QBLK) * 64;
  const char*   Kbyt = (const char*)(Kh  + (size_t)bh * SEQ * 64);
  const char*   Vbyt = (const char*)(VhT + (size_t)bh * 64 * SEQ);

  // staging: chunk c -> LDS byte c*16 (linear dest), pre-swizzled global src
  const int cA = tid, cB = tid + 512;
  const int kswA = (cA * 16) ^ (((cA >> 3) & 7) << 4);   // K tile: 8 chunks/row
  const int kswB = (cB * 16) ^ (((cB >> 3) & 7) << 4);
  const int vdA = cA >> 4, vdB = cB >> 4;                // VT tile: 16 chunks/row
  const int vswA = vdA * (SEQ * 2) + ((((cA & 15) ^ (vdA & 7))) << 4);
  const int vswB = vdB * (SEQ * 2) + ((((cB & 15) ^ (vdB & 7))) << 4);
  char* kldsA = Klds + cA * 16;
  char* kldsB = Klds + cB * 16;
  char* vldsA = VTlds + cA * 16;
  char* vldsB = VTlds + cB * 16;

  // Q fragments in regs (q = qg*16+ci, d-halves)
  const bf16x8 q0 = *(const bf16x8*)(Qp + (qg * 16 + ci) * 64 + 8 * g);
  const bf16x8 q1 = *(const bf16x8*)(Qp + (qg * 16 + ci) * 64 + 32 + 8 * g);

  const int kswz  = (ci & 7) << 4;
  const int krow0 = kg * 4096 + ci * 128;  // (kg*32+ci)*128 bytes

  // ---- pass 1: rowsums (2 K-tiles per barrier-pair, using both buffers) ----
  float rs = 0.f;
  for (int t = 0; t < NT; t += 2) {
    __syncthreads();
    gload16(Kbyt + (size_t)t * 16384 + kswA, kldsA);
    gload16(Kbyt + (size_t)t * 16384 + kswB, kldsB);
    gload16(Kbyt + (size_t)(t + 1) * 16384 + kswA, vldsA);
    gload16(Kbyt + (size_t)(t + 1) * 16384 + kswB, vldsB);
    __syncthreads();
#pragma unroll
    for (int hb = 0; hb < 2; ++hb) {
      const char* kt = smem + hb * 16384 + krow0;
#pragma unroll
      for (int s = 0; s < 2; ++s) {
        const bf16x8 k0 = *(const bf16x8*)(kt + s * 2048 + ((16 * g) ^ kswz));
        const bf16x8 k1 = *(const bf16x8*)(kt + s * 2048 + ((64 + 16 * g) ^ kswz));
        f32x4 sf = {0.f, 0.f, 0.f, 0.f};
        sf = mfma16(k0, q0, sf);
        sf = mfma16(k1, q1, sf);
#pragma unroll
        for (int r = 0; r < 4; ++r) rs += __builtin_amdgcn_exp2f(sf[r]);
      }
    }
  }
  rs += __shfl_xor(rs, 16);
  rs += __shfl_xor(rs, 32);
  if (lane < 16) rs_lds[w][lane] = rs;
  __syncthreads();
  if (tid < QBLK) {
    const int qg2 = tid >> 4;
    float tsum = 0.f;
#pragma unroll
    for (int kk = 0; kk < 4; ++kk) tsum += rs_lds[qg2 * 4 + kk][tid & 15];
    linv_lds[tid] = -__log2f(tsum);
  }
  __syncthreads();
  const float linv = linv_lds[qg * 16 + ci];

  // ---- pass 2: normalized attn stores + PV ----
  f32x4 apv[4] = {};
  float* orow = attn_out + ((size_t)bh * SEQ + qblk * QBLK + qg * 16 + ci) * SEQ +
                kg * 32 + 4 * g;

  for (int t = 0; t < NT; ++t) {
    __syncthreads();
    gload16(Kbyt + (size_t)t * 16384 + kswA, kldsA);
    gload16(Kbyt + (size_t)t * 16384 + kswB, kldsB);
    gload16(Vbyt + (size_t)t * 256 + vswA, vldsA);
    gload16(Vbyt + (size_t)t * 256 + vswB, vldsB);
    __syncthreads();

    f32x4 e[2];
#pragma unroll
    for (int s = 0; s < 2; ++s) {
      const char* kt = Klds + krow0 + s * 2048;
      const bf16x8 k0 = *(const bf16x8*)(kt + ((16 * g) ^ kswz));
      const bf16x8 k1 = *(const bf16x8*)(kt + ((64 + 16 * g) ^ kswz));
      f32x4 sf = {0.f, 0.f, 0.f, 0.f};
      sf = mfma16(k0, q0, sf);
      sf = mfma16(k1, q1, sf);
#pragma unroll
      for (int r = 0; r < 4; ++r) e[s][r] = __builtin_amdgcn_exp2f(sf[r] + linv);
      __builtin_nontemporal_store(e[s], (f32x4*)(orow + t * 128 + s * 16));
    }
    // PV: A-frag = own e's (virtual k-slots), B-frag = VT from swizzled LDS
    const bf16x8 pa = {(__bf16)e[0][0], (__bf16)e[0][1], (__bf16)e[0][2], (__bf16)e[0][3],
                       (__bf16)e[1][0], (__bf16)e[1][1], (__bf16)e[1][2], (__bf16)e[1][3]};
    const int inr0 = (64 * kg + 8 * g) ^ kswz;
    const int inr1 = (64 * kg + 32 + 8 * g) ^ kswz;
#pragma unroll
    for (int dt = 0; dt < 4; ++dt) {
      const char* vrow = VTlds + (dt * 16 + ci) * 256;
      const bf16x4 v0 = *(const bf16x4*)(vrow + inr0);
      const bf16x4 v1 = *(const bf16x4*)(vrow + inr1);
      const bf16x8 vb = {v0[0], v0[1], v0[2], v0[3], v1[0], v1[1], v1[2], v1[3]};
      apv[dt] = mfma16(pa, vb, apv[dt]);
    }
  }

  // ---- cross-wave (kg) PV reduce via LDS union ----
  __syncthreads();
  {
    const int base = (qg * 4 + kg) * 16;
#pragma unroll
    for (int dt = 0; dt < 4; ++dt)
#pragma unroll
      for (int r = 0; r < 4; ++r)
        pvf[(base + 4 * g + r) * 68 + dt * 16 + ci] = apv[dt][r];
  }
  __syncthreads();
  {
    const int qq  = tid >> 4;          // 0..31
    const int d0  = (tid & 15) * 4;
    const int qg2 = qq >> 4, row = qq & 15;
    f32x4 s = {0.f, 0.f, 0.f, 0.f};
#pragma unroll
    for (int kk = 0; kk < 4; ++kk)
      s += *(const f32x4*)&pvf[((qg2 * 4 + kk) * 16 + row) * 68 + d0];
    const int b = bh >> 4, h = bh & 15;
    const bf16x4 o = {(__bf16)s[0], (__bf16)s[1], (__bf16)s[2], (__bf16)s[3]};
    *(bf16x4*)&Cbuf[((size_t)b * SEQ + qblk * QBLK + qq) * FEA + h * 64 + d0] = o;
  }
}

// ------------------------------------------------------------------ launch ---
extern "C" void kernel_launch(void* const* d_in, const int* in_sizes, int n_in,
                              void* d_out, int out_size, void* d_ws, size_t ws_size,
                              hipStream_t stream) {
  const float* q    = (const float*)d_in[0];
  const float* k    = (const float*)d_in[1];
  const float* v    = (const float*)d_in[2];
  const float* wq_w = (const float*)d_in[3];
  const float* wq_b = (const float*)d_in[4];
  const float* wk_w = (const float*)d_in[5];
  const float* wk_b = (const float*)d_in[6];
  const float* wv_w = (const float*)d_in[7];
  const float* wv_b = (const float*)d_in[8];
  const float* fc_w = (const float*)d_in[9];
  const float* fc_b = (const float*)d_in[10];

  float* out0 = (float*)d_out;
  float* attn = out0 + (size_t)MROWS * FEA;  // second tuple output

  // bf16 scratch that dies before attn runs -> reuse the attn output region
  __bf16* Xq = (__bf16*)attn;
  __bf16* Xk = Xq + (size_t)MROWS * FEA;
  __bf16* Xv = Xk + (size_t)MROWS * FEA;
  __bf16* Wq = Xv + (size_t)MROWS * FEA;
  __bf16* Wk = Wq + (size_t)FEA * FEA;
  __bf16* Wv = Wk + (size_t)FEA * FEA;

  // persistent scratch (lives across attn) -> d_ws, 34 MiB
  __bf16* Qh  = (__bf16*)d_ws;
  __bf16* Kh  = Qh  + (size_t)MROWS * FEA;
  __bf16* VhT = Kh  + (size_t)MROWS * FEA;
  __bf16* Cb  = VhT + (size_t)MROWS * FEA;
  __bf16* Wfc = Cb  + (size_t)MROWS * FEA;

  ConvArgs ca;
  ca.seg[0] = {q,    Xq,  (MROWS * FEA) / 4, 1.0f};
  ca.seg[1] = {k,    Xk,  (MROWS * FEA) / 4, 1.0f};
  ca.seg[2] = {v,    Xv,  (MROWS * FEA) / 4, 1.0f};
  ca.seg[3] = {wq_w, Wq,  (FEA * FEA) / 4,   QK_SCALE};
  ca.seg[4] = {wk_w, Wk,  (FEA * FEA) / 4,   1.0f};
  ca.seg[5] = {wv_w, Wv,  (FEA * FEA) / 4,   1.0f};
  ca.seg[6] = {fc_w, Wfc, (FEA * FEA) / 4,   1.0f};
  convert_k<<<dim3(512, 7), 256, 0, stream>>>(ca);

  QkvArgs qa;
  qa.A[0] = Xq; qa.Bt[0] = Wq; qa.bias[0] = wq_b; qa.bscale[0] = QK_SCALE; qa.out[0] = Qh;
  qa.A[1] = Xk; qa.Bt[1] = Wk; qa.bias[1] = wk_b; qa.bscale[1] = 1.0f;     qa.out[1] = Kh;
  qa.A[2] = Xv; qa.Bt[2] = Wv; qa.bias[2] = wv_b; qa.bscale[2] = 1.0f;     qa.out[2] = VhT;
  gemm_qkv<<<dim3(MROWS / 128, FEA / 128, 3), 256, 0, stream>>>(qa);

  attn_fused<<<dim3((SEQ / QBLK) * NHEAD * 2), 512, 0, stream>>>(Qh, Kh, VhT, attn, Cb);

  gemm_fc<<<dim3(MROWS / 128, FEA / 128), 256, 0, stream>>>(Cb, Wfc, fc_b, out0);
}

// Round 6
// 236.066 us; speedup vs baseline: 2.3267x; 1.0136x over previous
//
#include <hip/hip_runtime.h>
#include <stdint.h>

#define DEV __device__ __forceinline__

using f32x4  = __attribute__((ext_vector_type(4))) float;
using bf16x8 = __attribute__((ext_vector_type(8))) __bf16;
using bf16x4 = __attribute__((ext_vector_type(4))) __bf16;

static constexpr int SEQ  = 2048;
static constexpr int FEA  = 1024;
static constexpr int NHEAD = 16;
static constexpr int MROWS = 4096;  // B*S
// scale folded into Wq: (1/sqrt(64)) * log2(e)  -> scores directly in exp2 domain
static constexpr float QK_SCALE = 0.18033688011112042f;

DEV f32x4 mfma16(bf16x8 a, bf16x8 b, f32x4 c) {
  return __builtin_amdgcn_mfma_f32_16x16x32_bf16(a, b, c, 0, 0, 0);
}

DEV void gload16(const void* g, void* l) {
  __builtin_amdgcn_global_load_lds((__attribute__((address_space(1))) void*)g,
                                   (__attribute__((address_space(3))) void*)l,
                                   16, 0, 0);
}

#define FENCE_VMCNT(n) asm volatile("s_waitcnt vmcnt(" #n ")" ::: "memory")
#define FENCE_LGKM0()  asm volatile("s_waitcnt lgkmcnt(0)" ::: "memory")

// ---------------------------------------------------------------- convert ---
struct ConvSeg { const float* src; __bf16* dst; int n4; float scale; };
struct ConvArgs { ConvSeg seg[7]; };

__global__ __launch_bounds__(256) void convert_k(ConvArgs a) {
  const ConvSeg sg = a.seg[blockIdx.y];
  const int stride = gridDim.x * blockDim.x;
  for (int i = blockIdx.x * blockDim.x + threadIdx.x; i < sg.n4; i += stride) {
    const f32x4 v = *(const f32x4*)(sg.src + (size_t)i * 4);
    bf16x4 o = {(__bf16)(v[0] * sg.scale), (__bf16)(v[1] * sg.scale),
                (__bf16)(v[2] * sg.scale), (__bf16)(v[3] * sg.scale)};
    *(bf16x4*)(sg.dst + (size_t)i * 4) = o;
  }
}

// ------------------------------------------------------------------- GEMM ---
// 128x128 tile, 4 waves, BK=64 (16 iters, 32 MFMA per barrier-pair).
// LDS tiles [128][64] bf16 (128B rows), XOR-swizzled ((row&7)<<4) via
// pre-swizzled global source + swizzled ds_read (both-sides rule).
DEV void gemm_core64(const __bf16* __restrict__ A, const __bf16* __restrict__ Bt,
                     char* lds, int row0, int col0, int tid, f32x4 (&acc)[4][4]) {
  char* Alds = lds;
  char* Blds = lds + 16384;
  constexpr int K = 1024;
  const int lane = tid & 63;
  const int w    = tid >> 6;
  const int ci   = lane & 15;
  const int g    = lane >> 4;
  const int wr   = w >> 1, wc = w & 1;

  const __bf16* gA[4]; const __bf16* gB[4];
  char* lA[4]; char* lB[4];
#pragma unroll
  for (int j = 0; j < 4; ++j) {
    const int c = tid + 256 * j;
    const int r = c >> 3, s = c & 7;
    const int gsw = (s ^ (r & 7)) * 8;     // pre-swizzled source column
    gA[j] = A  + (size_t)(row0 + r) * K + gsw;
    gB[j] = Bt + (size_t)(col0 + r) * K + gsw;
    lA[j] = Alds + c * 16;
    lB[j] = Blds + c * 16;
  }
  const int rsw = (ci & 7) << 4;

  for (int k0 = 0; k0 < K; k0 += 64) {
    __syncthreads();
#pragma unroll
    for (int j = 0; j < 4; ++j) {
      gload16(gA[j] + k0, lA[j]);
      gload16(gB[j] + k0, lB[j]);
    }
    __syncthreads();
#pragma unroll
    for (int kk = 0; kk < 2; ++kk) {
      bf16x8 af[4], bfr[4];
#pragma unroll
      for (int m = 0; m < 4; ++m)
        af[m] = *(const bf16x8*)(Alds + (wr * 64 + m * 16 + ci) * 128 +
                                 ((kk * 64 + g * 16) ^ rsw));
#pragma unroll
      for (int n = 0; n < 4; ++n)
        bfr[n] = *(const bf16x8*)(Blds + (wc * 64 + n * 16 + ci) * 128 +
                                  ((kk * 64 + g * 16) ^ rsw));
#pragma unroll
      for (int m = 0; m < 4; ++m)
#pragma unroll
        for (int n = 0; n < 4; ++n)
          acc[m][n] = mfma16(af[m], bfr[n], acc[m][n]);
    }
  }
}

// Batched q/k/v projection: grid.z picks the problem. z=0,1 -> [B,H,S,D]; z=2 -> [B,H,D,S].
struct QkvArgs {
  const __bf16* A[3];
  const __bf16* Bt[3];
  const float*  bias[3];
  float         bscale[3];
  __bf16*       out[3];
};

__global__ __launch_bounds__(256) void gemm_qkv(QkvArgs args) {
  __shared__ __align__(16) char lds[32768];
  const int z = blockIdx.z;
  const int tid = threadIdx.x;
  const int row0 = blockIdx.x * 128;
  const int col0 = blockIdx.y * 128;
  f32x4 acc[4][4] = {};
  gemm_core64(args.A[z], args.Bt[z], lds, row0, col0, tid, acc);

  const int lane = tid & 63;
  const int ci = lane & 15, g = lane >> 4;
  const int w = tid >> 6;
  const int wr = w >> 1, wc = w & 1;
  const float* bias = args.bias[z];
  const float bscale = args.bscale[z];
  __bf16* outp = args.out[z];
  const bool vt = (z == 2);
#pragma unroll
  for (int m = 0; m < 4; ++m)
#pragma unroll
    for (int n = 0; n < 4; ++n)
#pragma unroll
      for (int r = 0; r < 4; ++r) {
        const int gr = row0 + wr * 64 + m * 16 + 4 * g + r;
        const int gc = col0 + wc * 64 + n * 16 + ci;
        const float vv = acc[m][n][r] + bias[gc] * bscale;
        const int b = gr >> 11, s = gr & (SEQ - 1);
        const int h = gc >> 6,  d = gc & 63;
        if (!vt)
          outp[(((size_t)b * NHEAD + h) * SEQ + s) * 64 + d] = (__bf16)vv;
        else
          outp[(((size_t)b * NHEAD + h) * 64 + d) * SEQ + s] = (__bf16)vv;
      }
}

__global__ __launch_bounds__(256) void gemm_fc(const __bf16* __restrict__ A,
                                               const __bf16* __restrict__ Bt,
                                               const float* __restrict__ bias,
                                               float* __restrict__ outp) {
  __shared__ __align__(16) char lds[32768];
  const int tid = threadIdx.x;
  const int row0 = blockIdx.x * 128;
  const int col0 = blockIdx.y * 128;
  f32x4 acc[4][4] = {};
  gemm_core64(A, Bt, lds, row0, col0, tid, acc);

  const int lane = tid & 63;
  const int ci = lane & 15, g = lane >> 4;
  const int w = tid >> 6;
  const int wr = w >> 1, wc = w & 1;
#pragma unroll
  for (int m = 0; m < 4; ++m)
#pragma unroll
    for (int n = 0; n < 4; ++n)
#pragma unroll
      for (int r = 0; r < 4; ++r) {
        const int gr = row0 + wr * 64 + m * 16 + 4 * g + r;
        const int gc = col0 + wc * 64 + n * 16 + ci;
        const float vv = fmaxf(acc[m][n][r] + bias[gc], 0.0f);
        __builtin_nontemporal_store(vv, &outp[(size_t)gr * FEA + gc]);
      }
}

// -------------------------------------------------------------- attention ---
// One block = 32 q-rows of one (b,h). 512 thr (8 waves): wave = (qg=w>>2, kg=w&3).
// Counted-vmcnt double-buffered staging (T3/T4-lite): K/V 16KB buffer pairs at
// integer offsets in one LDS blob (no LDS-pointer arrays: hipcc can't emit
// addrspacecast initializers). Raw s_barrier + vmcnt(N) keeps next tile's
// loads in flight across barriers.
// Pass 1: QK rowsums.  Pass 2: recompute QK, stream normalized fp32 attn from
// registers (nontemporal), PV via virtual-k permutation from swizzled V LDS.
static constexpr int QBLK = 32;
static constexpr int KVB  = 128;
static constexpr int NT   = SEQ / KVB;  // 16

__global__ __launch_bounds__(512, 4) void attn_fused(const __bf16* __restrict__ Qh,
                                                     const __bf16* __restrict__ Kh,
                                                     const __bf16* __restrict__ VhT,
                                                     float* __restrict__ attn_out,
                                                     __bf16* __restrict__ Cbuf) {
  // layout: [K0 16K][V0 16K][K1 16K][V1 16K]; buffer b at offset b*32768
  __shared__ __align__(16) char smem[65536];
  __shared__ float rs_lds[8][16];
  __shared__ float linv_lds[QBLK];
  float* pvf = (float*)smem;

  const int tid  = threadIdx.x;
  const int lane = tid & 63;
  const int w    = tid >> 6;
  const int ci   = lane & 15;
  const int g    = lane >> 4;
  const int qg   = w >> 2;   // 0..1 (q-group of 16 rows)
  const int kg   = w & 3;    // 0..3 (32-k window within tile)

  // XCD-aware swizzle: each XCD owns 4 heads -> K/VT working set 2MB < L2
  const int id   = blockIdx.x;
  const int xcd  = id & 7;
  const int idx  = id >> 3;
  const int bh   = xcd * 4 + (idx >> 6);
  const int qblk = idx & 63;

  const __bf16* Qp   = Qh + ((size_t)bh * SEQ + qblk * QBLK) * 64;
  const char*   Kbyt = (const char*)(Kh  + (size_t)bh * SEQ * 64);
  const char*   Vbyt = (const char*)(VhT + (size_t)bh * 64 * SEQ);

  // staging: chunk c -> LDS byte c*16 (linear dest), pre-swizzled global src
  const int cA = tid, cB = tid + 512;
  const int kgoffA = ((cA >> 3) * 128) + (((cA & 7) ^ ((cA >> 3) & 7)) * 16);
  const int kgoffB = ((cB >> 3) * 128) + (((cB & 7) ^ ((cB >> 3) & 7)) * 16);
  const int vdA = cA >> 4, vdB = cB >> 4;
  const int vgoffA = vdA * (SEQ * 2) + (((cA & 15) ^ (vdA & 7)) * 16);
  const int vgoffB = vdB * (SEQ * 2) + (((cB & 15) ^ (vdB & 7)) * 16);

#define STAGE_K(t, boff) { gload16(Kbyt + (size_t)(t) * 16384 + kgoffA, smem + (boff) + cA * 16); \
                           gload16(Kbyt + (size_t)(t) * 16384 + kgoffB, smem + (boff) + cB * 16); }
#define STAGE_V(t, boff) { gload16(Vbyt + (size_t)(t) * 256 + vgoffA, smem + 16384 + (boff) + cA * 16); \
                           gload16(Vbyt + (size_t)(t) * 256 + vgoffB, smem + 16384 + (boff) + cB * 16); }

  // Q fragments in regs (q = qg*16+ci, d-halves)
  const bf16x8 q0 = *(const bf16x8*)(Qp + (qg * 16 + ci) * 64 + 8 * g);
  const bf16x8 q1 = *(const bf16x8*)(Qp + (qg * 16 + ci) * 64 + 32 + 8 * g);

  const int kswz  = (ci & 7) << 4;
  const int krow0 = kg * 4096 + ci * 128;  // (kg*32+ci)*128 bytes

  // ---- pass 1: rowsums (K double-buffered, counted vmcnt) ----
  float rs = 0.f;
  STAGE_K(0, 0);
  for (int t = 0; t < NT; ++t) {
    const int coff = (t & 1) << 15;
    if (t < NT - 1) { STAGE_K(t + 1, coff ^ 32768); FENCE_VMCNT(2); }
    else            { FENCE_VMCNT(0); }
    __builtin_amdgcn_s_barrier();
    const char* kt = smem + coff + krow0;
#pragma unroll
    for (int s = 0; s < 2; ++s) {
      const bf16x8 k0 = *(const bf16x8*)(kt + s * 2048 + ((16 * g) ^ kswz));
      const bf16x8 k1 = *(const bf16x8*)(kt + s * 2048 + ((64 + 16 * g) ^ kswz));
      f32x4 sf = {0.f, 0.f, 0.f, 0.f};
      sf = mfma16(k0, q0, sf);
      sf = mfma16(k1, q1, sf);
#pragma unroll
      for (int r = 0; r < 4; ++r) rs += __builtin_amdgcn_exp2f(sf[r]);
    }
    FENCE_LGKM0();
    __builtin_amdgcn_s_barrier();
  }
  rs += __shfl_xor(rs, 16);
  rs += __shfl_xor(rs, 32);
  if (lane < 16) rs_lds[w][lane] = rs;
  __syncthreads();
  if (tid < QBLK) {
    const int qg2 = tid >> 4;
    float tsum = 0.f;
#pragma unroll
    for (int kk = 0; kk < 4; ++kk) tsum += rs_lds[qg2 * 4 + kk][tid & 15];
    linv_lds[tid] = -__log2f(tsum);
  }
  __syncthreads();
  const float linv = linv_lds[qg * 16 + ci];

  // ---- pass 2: normalized attn stores + PV (K+V double-buffered) ----
  f32x4 apv[4] = {};
  float* orow = attn_out + ((size_t)bh * SEQ + qblk * QBLK + qg * 16 + ci) * SEQ +
                kg * 32 + 4 * g;

  STAGE_K(0, 0);
  STAGE_V(0, 0);
  for (int t = 0; t < NT; ++t) {
    const int coff = (t & 1) << 15;
    if (t < NT - 1) { STAGE_K(t + 1, coff ^ 32768); STAGE_V(t + 1, coff ^ 32768); FENCE_VMCNT(4); }
    else            { FENCE_VMCNT(0); }
    __builtin_amdgcn_s_barrier();

    f32x4 e[2];
#pragma unroll
    for (int s = 0; s < 2; ++s) {
      const char* kt = smem + coff + krow0 + s * 2048;
      const bf16x8 k0 = *(const bf16x8*)(kt + ((16 * g) ^ kswz));
      const bf16x8 k1 = *(const bf16x8*)(kt + ((64 + 16 * g) ^ kswz));
      f32x4 sf = {0.f, 0.f, 0.f, 0.f};
      sf = mfma16(k0, q0, sf);
      sf = mfma16(k1, q1, sf);
#pragma unroll
      for (int r = 0; r < 4; ++r) e[s][r] = __builtin_amdgcn_exp2f(sf[r] + linv);
      __builtin_nontemporal_store(e[s], (f32x4*)(orow + t * 128 + s * 16));
    }
    // PV: A-frag = own e's (virtual k-slots), B-frag = VT from swizzled LDS
    const bf16x8 pa = {(__bf16)e[0][0], (__bf16)e[0][1], (__bf16)e[0][2], (__bf16)e[0][3],
                       (__bf16)e[1][0], (__bf16)e[1][1], (__bf16)e[1][2], (__bf16)e[1][3]};
    const int inr0 = (64 * kg + 8 * g) ^ kswz;
    const int inr1 = (64 * kg + 32 + 8 * g) ^ kswz;
#pragma unroll
    for (int dt = 0; dt < 4; ++dt) {
      const char* vrow = smem + 16384 + coff + (dt * 16 + ci) * 256;
      const bf16x4 v0 = *(const bf16x4*)(vrow + inr0);
      const bf16x4 v1 = *(const bf16x4*)(vrow + inr1);
      const bf16x8 vb = {v0[0], v0[1], v0[2], v0[3], v1[0], v1[1], v1[2], v1[3]};
      apv[dt] = mfma16(pa, vb, apv[dt]);
    }
    FENCE_LGKM0();
    __builtin_amdgcn_s_barrier();
  }

  // ---- cross-wave (kg) PV reduce via LDS union ----
  {
    const int base = (qg * 4 + kg) * 16;
#pragma unroll
    for (int dt = 0; dt < 4; ++dt)
#pragma unroll
      for (int r = 0; r < 4; ++r)
        pvf[(base + 4 * g + r) * 68 + dt * 16 + ci] = apv[dt][r];
  }
  __syncthreads();
  {
    const int qq  = tid >> 4;          // 0..31
    const int d0  = (tid & 15) * 4;
    const int qg2 = qq >> 4, row = qq & 15;
    f32x4 s = {0.f, 0.f, 0.f, 0.f};
#pragma unroll
    for (int kk = 0; kk < 4; ++kk)
      s += *(const f32x4*)&pvf[((qg2 * 4 + kk) * 16 + row) * 68 + d0];
    const int b = bh >> 4, h = bh & 15;
    const bf16x4 o = {(__bf16)s[0], (__bf16)s[1], (__bf16)s[2], (__bf16)s[3]};
    *(bf16x4*)&Cbuf[((size_t)b * SEQ + qblk * QBLK + qq) * FEA + h * 64 + d0] = o;
  }
#undef STAGE_K
#undef STAGE_V
}

// ------------------------------------------------------------------ launch ---
extern "C" void kernel_launch(void* const* d_in, const int* in_sizes, int n_in,
                              void* d_out, int out_size, void* d_ws, size_t ws_size,
                              hipStream_t stream) {
  const float* q    = (const float*)d_in[0];
  const float* k    = (const float*)d_in[1];
  const float* v    = (const float*)d_in[2];
  const float* wq_w = (const float*)d_in[3];
  const float* wq_b = (const float*)d_in[4];
  const float* wk_w = (const float*)d_in[5];
  const float* wk_b = (const float*)d_in[6];
  const float* wv_w = (const float*)d_in[7];
  const float* wv_b = (const float*)d_in[8];
  const float* fc_w = (const float*)d_in[9];
  const float* fc_b = (const float*)d_in[10];

  float* out0 = (float*)d_out;
  float* attn = out0 + (size_t)MROWS * FEA;  // second tuple output

  // bf16 scratch that dies before attn runs -> reuse the attn output region
  __bf16* Xq = (__bf16*)attn;
  __bf16* Xk = Xq + (size_t)MROWS * FEA;
  __bf16* Xv = Xk + (size_t)MROWS * FEA;
  __bf16* Wq = Xv + (size_t)MROWS * FEA;
  __bf16* Wk = Wq + (size_t)FEA * FEA;
  __bf16* Wv = Wk + (size_t)FEA * FEA;

  // persistent scratch (lives across attn) -> d_ws, 34 MiB
  __bf16* Qh  = (__bf16*)d_ws;
  __bf16* Kh  = Qh  + (size_t)MROWS * FEA;
  __bf16* VhT = Kh  + (size_t)MROWS * FEA;
  __bf16* Cb  = VhT + (size_t)MROWS * FEA;
  __bf16* Wfc = Cb  + (size_t)MROWS * FEA;

  ConvArgs ca;
  ca.seg[0] = {q,    Xq,  (MROWS * FEA) / 4, 1.0f};
  ca.seg[1] = {k,    Xk,  (MROWS * FEA) / 4, 1.0f};
  ca.seg[2] = {v,    Xv,  (MROWS * FEA) / 4, 1.0f};
  ca.seg[3] = {wq_w, Wq,  (FEA * FEA) / 4,   QK_SCALE};
  ca.seg[4] = {wk_w, Wk,  (FEA * FEA) / 4,   1.0f};
  ca.seg[5] = {wv_w, Wv,  (FEA * FEA) / 4,   1.0f};
  ca.seg[6] = {fc_w, Wfc, (FEA * FEA) / 4,   1.0f};
  convert_k<<<dim3(512, 7), 256, 0, stream>>>(ca);

  QkvArgs qa;
  qa.A[0] = Xq; qa.Bt[0] = Wq; qa.bias[0] = wq_b; qa.bscale[0] = QK_SCALE; qa.out[0] = Qh;
  qa.A[1] = Xk; qa.Bt[1] = Wk; qa.bias[1] = wk_b; qa.bscale[1] = 1.0f;     qa.out[1] = Kh;
  qa.A[2] = Xv; qa.Bt[2] = Wv; qa.bias[2] = wv_b; qa.bscale[2] = 1.0f;     qa.out[2] = VhT;
  gemm_qkv<<<dim3(MROWS / 128, FEA / 128, 3), 256, 0, stream>>>(qa);

  attn_fused<<<dim3((SEQ / QBLK) * NHEAD * 2), 512, 0, stream>>>(Qh, Kh, VhT, attn, Cb);

  gemm_fc<<<dim3(MROWS / 128, FEA / 128), 256, 0, stream>>>(Cb, Wfc, fc_b, out0);
}